// Round 2
// baseline (196.346 us; speedup 1.0000x reference)
//
#include <hip/hip_runtime.h>

// filtfilt butter(4,0.2), 512 rows x T=32768 fp32.
//  - reference's scale/unscale is linear-homogeneous -> cancels exactly -> skipped.
//  - poles |p|max ~0.796: fwd warm-up 32 (7e-4 abs), bwd warm-up 28 (~5e-3); thr 7e-2.
//  - R5 post-mortem: kC=32 @ launch_bounds(256,8) forced VGPR<=64 -> spilled arc/wu
//    to scratch (VGPR=32 reported, WRITE_SIZE +20MB) -> 68us. Occupancy isn't the
//    lever; per-thread serial chain latency is (VALUBusy 25% @ both 16 and 31 w/CU).
//  - R6: TWO independent 32-sample chains (A,B = adjacent chunks) per thread.
//    Same footprint/grid as R4 (64 outputs/thread, 4096 waves, 16/CU), but the
//    serial span drops 216 -> ~152 STEPs and is dual-issue almost throughout.
//    Structural win: A's bwd warm-up inputs == B's fwd outputs (arcB), already in
//    registers -> A needs no forward-continue. B's last-chunk tail is zero-padded
//    into wuB so the bwd warm-up is uniform (STEP(0) preserves zero ICs).
//  - forward intermediates in registers as packed fp16 pairs. CRITICAL: native
//    ext_vector_type(2) __fp16 (return type of __builtin_amdgcn_cvt_pkrtz), NOT
//    __half2 (class type) — __half2 arrays fail SROA and spill (R3).
//  - no LDS; __launch_bounds__(64,4) -> VGPR cap 128 (peak live ~110), 16 waves/CU.

typedef __fp16 h2 __attribute__((ext_vector_type(2)));

constexpr int kT   = 32768;
constexpr int kC   = 32;          // outputs per chain; 2 chains per thread
constexpr int kWF  = 32;          // forward warm-up samples
constexpr int kNP  = kT / (2 * kC);   // 512 pairs/row
constexpr int kTPB = 64;

#define B0 0.0048243445989025905f
#define B1 0.019297378395610362f
#define B2 0.028946067593415543f
#define B3 0.019297378395610362f
#define B4 0.0048243445989025905f
#define NA1 2.369513007182038f
#define NA2 (-2.3139884144002064f)
#define NA3 1.0546654058785661f
#define NA4 (-0.18737949236818502f)

// Direct-form II transposed step, chain A / chain B.
#define STEPA(xv) do { \
    ya  = fmaf(B0, (xv), za1); \
    za1 = fmaf(NA1, ya, fmaf(B1, (xv), za2)); \
    za2 = fmaf(NA2, ya, fmaf(B2, (xv), za3)); \
    za3 = fmaf(NA3, ya, fmaf(B3, (xv), za4)); \
    za4 = fmaf(NA4, ya, B4 * (xv)); \
} while (0)

#define STEPB(xv) do { \
    yb  = fmaf(B0, (xv), zb1); \
    zb1 = fmaf(NA1, yb, fmaf(B1, (xv), zb2)); \
    zb2 = fmaf(NA2, yb, fmaf(B2, (xv), zb3)); \
    zb3 = fmaf(NA3, yb, fmaf(B3, (xv), zb4)); \
    zb4 = fmaf(NA4, yb, B4 * (xv)); \
} while (0)

#define PACK2A(va, vb, DST) do { \
    STEPA(va); float _t = ya; \
    STEPA(vb); DST = __builtin_amdgcn_cvt_pkrtz(_t, ya); \
} while (0)

#define PACK2B(va, vb, DST) do { \
    STEPB(va); float _t = yb; \
    STEPB(vb); DST = __builtin_amdgcn_cvt_pkrtz(_t, yb); \
} while (0)

__global__ __launch_bounds__(kTPB, 4)
void filtfilt_kernel(const float* __restrict__ x, float* __restrict__ out) {
    const int tid  = blockIdx.x * kTPB + threadIdx.x;
    const int row  = tid >> 9;              // 512 pairs/row
    const int pr   = tid & (kNP - 1);
    const bool first = (pr == 0);
    const bool last  = (pr == kNP - 1);
    const float* __restrict__ xr = x + (size_t)row * kT;
    float* __restrict__ outr     = out + (size_t)row * kT;
    const int s = pr * (2 * kC);            // A covers [s,s+32), B [s+32,s+64)

    h2 arcA[16], arcB[16];   // fwd outputs of A / B main regions (fp16-packed)
    h2 wuB[14];              // B bwd warm-up samples [s+64,s+92); last: padded tail

    float za1 = 0.f, za2 = 0.f, za3 = 0.f, za4 = 0.f, ya;
    float zb1 = 0.f, zb2 = 0.f, zb3 = 0.f, zb4 = 0.f, yb;

    const float4* mp = (const float4*)(xr + s);
    float4 m0 = mp[0], m1 = mp[1], m2 = mp[2], m3 = mp[3];
    float4 m4 = mp[4], m5 = mp[5], m6 = mp[6], m7 = mp[7];

    // ---- stage 1: A fwd warm-up (left-ext or x[s-32,s)) || B fwd warm-up x[s,s+32)
    {
        // guarded pointer: first-pair lanes read x[0..31] harmlessly (ignored via select)
        const float4* wp = (const float4*)(xr + (first ? 0 : (s - kWF)));
        float4 w0 = wp[0], w1 = wp[1], w2 = wp[2], w3 = wp[3];
        float4 w4 = wp[4], w5 = wp[5], w6 = wp[6], w7 = wp[7];
        float wf[32] = {w0.x,w0.y,w0.z,w0.w, w1.x,w1.y,w1.z,w1.w,
                        w2.x,w2.y,w2.z,w2.w, w3.x,w3.y,w3.z,w3.w,
                        w4.x,w4.y,w4.z,w4.w, w5.x,w5.y,w5.z,w5.w,
                        w6.x,w6.y,w6.z,w6.w, w7.x,w7.y,w7.z,w7.w};
        float xa[16] = {m0.x,m0.y,m0.z,m0.w, m1.x,m1.y,m1.z,m1.w,
                        m2.x,m2.y,m2.z,m2.w, m3.x,m3.y,m3.z,m3.w};
        float mf[32] = {m0.x,m0.y,m0.z,m0.w, m1.x,m1.y,m1.z,m1.w,
                        m2.x,m2.y,m2.z,m2.w, m3.x,m3.y,m3.z,m3.w,
                        m4.x,m4.y,m4.z,m4.w, m5.x,m5.y,m5.z,m5.w,
                        m6.x,m6.y,m6.z,m6.w, m7.x,m7.y,m7.z,m7.w};
        #pragma unroll
        for (int i = 0; i < 32; ++i) {
            // first pair: 17 zero-steps (state stays 0) then 15 exact left-ext steps
            float ext = (i < 17) ? 0.f : fmaf(2.f, xa[0], -xa[32 - i]);
            float av  = first ? ext : wf[i];
            STEPA(av);
            STEPB(mf[i]);
        }
    }

    // ---- stage 2: A main x[s,s+32) -> arcA || B main x[s+32,s+64) -> arcB ----
    {
        float4 m8  = mp[8],  m9  = mp[9],  m10 = mp[10], m11 = mp[11];
        float4 m12 = mp[12], m13 = mp[13], m14 = mp[14], m15 = mp[15];
        float ma[32] = {m0.x,m0.y,m0.z,m0.w, m1.x,m1.y,m1.z,m1.w,
                        m2.x,m2.y,m2.z,m2.w, m3.x,m3.y,m3.z,m3.w,
                        m4.x,m4.y,m4.z,m4.w, m5.x,m5.y,m5.z,m5.w,
                        m6.x,m6.y,m6.z,m6.w, m7.x,m7.y,m7.z,m7.w};
        float mb[32] = {m8.x,m8.y,m8.z,m8.w,  m9.x,m9.y,m9.z,m9.w,
                        m10.x,m10.y,m10.z,m10.w, m11.x,m11.y,m11.z,m11.w,
                        m12.x,m12.y,m12.z,m12.w, m13.x,m13.y,m13.z,m13.w,
                        m14.x,m14.y,m14.z,m14.w, m15.x,m15.y,m15.z,m15.w};
        #pragma unroll
        for (int i = 0; i < 16; ++i) {
            PACK2A(ma[2 * i], ma[2 * i + 1], arcA[i]);
            PACK2B(mb[2 * i], mb[2 * i + 1], arcB[i]);
        }
    }

    // ---- stage 3: A bwd warm-up over arcB (28, zero ICs) || B fwd continue ----
    za1 = za2 = za3 = za4 = 0.f;
    if (!last) {
        // B continue: x[s+64, s+92) -> wuB
        float4 d0 = mp[16], d1 = mp[17], d2 = mp[18], d3 = mp[19];
        float4 d4 = mp[20], d5 = mp[21], d6 = mp[22];
        float df[28] = {d0.x,d0.y,d0.z,d0.w, d1.x,d1.y,d1.z,d1.w,
                        d2.x,d2.y,d2.z,d2.w, d3.x,d3.y,d3.z,d3.w,
                        d4.x,d4.y,d4.z,d4.w, d5.x,d5.y,d5.z,d5.w,
                        d6.x,d6.y,d6.z,d6.w};
        #pragma unroll
        for (int j = 0; j < 14; ++j) {
            const int k = 13 - j;
            float tb;
            STEPA((float)arcB[k].y); STEPB(df[2 * j]);     tb = yb;
            STEPA((float)arcB[k].x); STEPB(df[2 * j + 1]); wuB[j] = __builtin_amdgcn_cvt_pkrtz(tb, yb);
        }
    } else {
        // exact right odd-extension: 15 samples, zero-padded to the uniform
        // 28-slot consumption order (13 leading zeros keep zero ICs intact)
        const float4* e4 = (const float4*)(xr + kT - 16);
        float4 b0 = e4[0], b1 = e4[1], b2 = e4[2], b3 = e4[3];
        float xe[16] = {b0.x,b0.y,b0.z,b0.w, b1.x,b1.y,b1.z,b1.w,
                        b2.x,b2.y,b2.z,b2.w, b3.x,b3.y,b3.z,b3.w};
        float pend = 0.f;
        #pragma unroll
        for (int r = 0; r < 15; ++r) {
            float xv = fmaf(2.f, xe[15], -xe[14 - r]);
            STEPB(xv);
            if ((r & 1) == 0) pend = yb;
            else wuB[r >> 1] = __builtin_amdgcn_cvt_pkrtz(pend, yb);
        }
        wuB[7] = __builtin_amdgcn_cvt_pkrtz(pend, 0.f);   // (y14, 0)
        #pragma unroll
        for (int j = 8; j < 14; ++j) wuB[j] = __builtin_amdgcn_cvt_pkrtz(0.f, 0.f);
        // A bwd warm-up (duplicated here so every lane runs it exactly once)
        #pragma unroll
        for (int k = 13; k >= 0; --k) {
            STEPA((float)arcB[k].y);
            STEPA((float)arcB[k].x);
        }
    }

    // ---- stage 4: A bwd main -> out[s,s+32) || B bwd warm-up (uniform 28) ----
    zb1 = zb2 = zb3 = zb4 = 0.f;
    float4* opa = (float4*)(outr + s);
    #pragma unroll
    for (int gi = 7; gi >= 0; --gi) {
        float4 o; float v;
        v = (float)arcA[2 * gi + 1].y; STEPA(v); o.w = ya;
        if (gi > 0) { v = (float)wuB[2 * gi - 1].y; STEPB(v); }
        v = (float)arcA[2 * gi + 1].x; STEPA(v); o.z = ya;
        if (gi > 0) { v = (float)wuB[2 * gi - 1].x; STEPB(v); }
        v = (float)arcA[2 * gi + 0].y; STEPA(v); o.y = ya;
        if (gi > 0) { v = (float)wuB[2 * gi - 2].y; STEPB(v); }
        v = (float)arcA[2 * gi + 0].x; STEPA(v); o.x = ya;
        if (gi > 0) { v = (float)wuB[2 * gi - 2].x; STEPB(v); }
        opa[gi] = o;
    }

    // ---- stage 5: B bwd main -> out[s+32,s+64) ----
    float4* opb = (float4*)(outr + s + kC);
    #pragma unroll
    for (int gi = 7; gi >= 0; --gi) {
        float4 o; float v;
        v = (float)arcB[2 * gi + 1].y; STEPB(v); o.w = yb;
        v = (float)arcB[2 * gi + 1].x; STEPB(v); o.z = yb;
        v = (float)arcB[2 * gi + 0].y; STEPB(v); o.y = yb;
        v = (float)arcB[2 * gi + 0].x; STEPB(v); o.x = yb;
        opb[gi] = o;
    }
}

extern "C" void kernel_launch(void* const* d_in, const int* in_sizes, int n_in,
                              void* d_out, int out_size, void* d_ws, size_t ws_size,
                              hipStream_t stream) {
    const float* x = (const float*)d_in[0];
    float* out     = (float*)d_out;
    const int rows   = in_sizes[0] / kT;            // 512
    const int blocks = rows * kNP / kTPB;           // 4096
    filtfilt_kernel<<<blocks, kTPB, 0, stream>>>(x, out);
}

// Round 3
// 119.620 us; speedup vs baseline: 1.6414x; 1.6414x over previous
//
#include <hip/hip_runtime.h>

// filtfilt butter(4,0.2), 512 rows x T=32768 fp32.  R7: LDS-coalesced design.
//  - R5/R6 post-mortem: both spilled (forced VGPR caps / giant per-thread archives).
//    R4's true limiter: scattered per-lane access (64 lanes x 256B stride -> 64
//    transactions/instr, ~2560/wave) + serial chain @ 16 waves/CU.
//  - R7: wave covers 2048-sample segment; coalesced float4 global I/O; fp16 data
//    staged in a 4224B LDS slice [pre32|2048|post32]; XOR swizzle ((lo>>7)&7)<<4
//    for conflict-free 64B-strided b128 chunk reads. Fwd Y overwrites X in place;
//    bwd warm-up reads NEIGHBOR lane's Y from LDS (replaces R4's per-thread
//    28-step forward-continue). Only lane 63 runs a divergent continue (seam).
//  - wave-synchronous: slices are per-wave, DS ops execute in order within a wave
//    -> no __syncthreads; asm memory fences stop compiler reordering.
//  - exact paths kept: seg0/lane0 left odd-ext (17 zeros + 15 ext in pre slot),
//    last-seg/lane63 right odd-ext (15 ext y + zero-pad, R6 trick).
//  - launch_bounds(256,4): cap 128 VGPR -- do NOT force 8 waves/EU (R5 lesson).

typedef __fp16 h2 __attribute__((ext_vector_type(2)));
typedef __fp16 h4 __attribute__((ext_vector_type(4)));
typedef __fp16 h8 __attribute__((ext_vector_type(8)));

constexpr int kT      = 32768;
constexpr int kSeg    = 2048;          // samples per wave
constexpr int kNSeg   = kT / kSeg;     // 16
constexpr int kTPB    = 256;           // 4 independent waves / block
constexpr int kSliceB = 4224;          // 64B pre + 4096B main + 64B post

#define B0 0.0048243445989025905f
#define B1 0.019297378395610362f
#define B2 0.028946067593415543f
#define B3 0.019297378395610362f
#define B4 0.0048243445989025905f
#define NA1 2.369513007182038f
#define NA2 (-2.3139884144002064f)
#define NA3 1.0546654058785661f
#define NA4 (-0.18737949236818502f)

#define STEPF(xv) do { \
    y  = fmaf(B0, (xv), z1); \
    z1 = fmaf(NA1, y, fmaf(B1, (xv), z2)); \
    z2 = fmaf(NA2, y, fmaf(B2, (xv), z3)); \
    z3 = fmaf(NA3, y, fmaf(B3, (xv), z4)); \
    z4 = fmaf(NA4, y, B4 * (xv)); \
} while (0)

#define PK(a, b) __builtin_bit_cast(int, __builtin_amdgcn_cvt_pkrtz((a), (b)))

__device__ __forceinline__ int swz(int lo) { return lo ^ (((lo >> 7) & 7) << 4); }

__global__ __launch_bounds__(kTPB, 4)
void filtfilt_kernel(const float* __restrict__ x, float* __restrict__ out) {
    __shared__ __align__(16) char lds[4 * kSliceB];
    const int t  = threadIdx.x;
    const int l  = t & 63;                       // lane == chunk index in segment
    const int wv = t >> 6;
    const int W  = blockIdx.x * 4 + wv;
    const int row = W >> 4;
    const int seg = W & (kNSeg - 1);
    const float* __restrict__ xr   = x   + (size_t)row * kT + seg * kSeg;
    float* __restrict__ outr       = out + (size_t)row * kT + seg * kSeg;
    char* Lb = lds + wv * kSliceB;
    const bool haspre  = (seg > 0);
    const bool haspost = (seg < kNSeg - 1);

    // ================= stage: coalesced global -> fp16 LDS =================
    const float4* xp = (const float4*)xr;
    float4 mv[8];
    #pragma unroll
    for (int i = 0; i < 8; ++i) mv[i] = xp[i * 64 + l];
    float4 pre4 = {0.f, 0.f, 0.f, 0.f}, post4 = {0.f, 0.f, 0.f, 0.f};
    if (l < 8) {
        if (haspre)  pre4  = *(const float4*)(xr - 32 + l * 4);
        if (haspost) post4 = *(const float4*)(xr + kSeg + l * 4);
    }
    #pragma unroll
    for (int i = 0; i < 8; ++i) {
        int lo = swz(64 + i * 512 + 8 * l);
        int2 wi = { PK(mv[i].x, mv[i].y), PK(mv[i].z, mv[i].w) };
        *(int2*)(Lb + lo) = wi;
    }
    if (l < 8) {
        if (haspre) {                            // pre slot: x[sb-32, sb)
            int2 wi = { PK(pre4.x, pre4.y), PK(pre4.z, pre4.w) };
            *(int2*)(Lb + 8 * l) = wi;           // [0,64): identity under swz
        }
        if (haspost) {                           // post slot: x[sb+2048, +32)
            int2 wi = { PK(post4.x, post4.y), PK(post4.z, post4.w) };
            *(int2*)(Lb + 4160 + 8 * l) = wi;    // identity under swz
        }
    }
    asm volatile("s_waitcnt lgkmcnt(0)" ::: "memory");
    if (!haspre && l < 8) {
        // seg 0: pre = 17 zeros + 15 left odd-ext (exact; zero-IC-preserving pad)
        const __fp16* xs = (const __fp16*)(Lb + 64);   // samples 0..31, identity
        float x0 = (float)xs[0];
        float v[4];
        #pragma unroll
        for (int r = 0; r < 4; ++r) {
            int k = 4 * l + r;
            v[r] = (k < 17) ? 0.f : fmaf(2.f, x0, -(float)xs[32 - k]);
        }
        int2 wi = { PK(v[0], v[1]), PK(v[2], v[3]) };
        *(int2*)(Lb + 8 * l) = wi;
    }
    asm volatile("" ::: "memory");

    // ================= phase 1: fwd warm-up (32, chunk l-1 / pre) ==========
    float z1 = 0.f, z2 = 0.f, z3 = 0.f, z4 = 0.f, y;
    {
        const int wb = l * 64;
        const int xv = ((wb >> 7) & 7) << 4;
        #pragma unroll
        for (int j = 0; j < 4; ++j) {
            h8 v = *(const h8*)(Lb + ((wb + 16 * j) ^ xv));
            #pragma unroll
            for (int e = 0; e < 8; ++e) STEPF((float)v[e]);
        }
    }

    // ================= phase 2: fwd main (32), Y over X in place ===========
    h8 tailA, tailB;    // raw X samples 16..31 of own chunk (for last-seg ext)
    {
        const int mb = (l + 1) * 64;
        const int xm = ((mb >> 7) & 7) << 4;
        #pragma unroll
        for (int j = 0; j < 4; ++j) {
            char* p = Lb + ((mb + 16 * j) ^ xm);
            h8 v = *(const h8*)p;
            if (j == 2) tailA = v;
            if (j == 3) tailB = v;
            float q[8];
            #pragma unroll
            for (int e = 0; e < 8; ++e) { STEPF((float)v[e]); q[e] = y; }
            int4 wi = { PK(q[0], q[1]), PK(q[2], q[3]), PK(q[4], q[5]), PK(q[6], q[7]) };
            *(int4*)p = wi;
        }
    }

    // ====== phase 2.5 (lane 63 only): build W into post region =============
    if (l == 63) {
        if (haspost) {
            // continue fwd chain over post X (28 steps), write y -> post
            #pragma unroll
            for (int g = 0; g < 4; ++g) {
                h8 v = *(const h8*)(Lb + 4160 + 16 * g);
                if (g < 3) {
                    float q[8];
                    #pragma unroll
                    for (int e = 0; e < 8; ++e) { STEPF((float)v[e]); q[e] = y; }
                    int4 wi = { PK(q[0], q[1]), PK(q[2], q[3]), PK(q[4], q[5]), PK(q[6], q[7]) };
                    *(int4*)(Lb + 4160 + 16 * g) = wi;
                } else {
                    float q[4];
                    #pragma unroll
                    for (int e = 0; e < 4; ++e) { STEPF((float)v[e]); q[e] = y; }
                    int4 wi = { PK(q[0], q[1]), PK(q[2], q[3]), 0, 0 };
                    *(int4*)(Lb + 4160 + 16 * g) = wi;
                }
            }
        } else {
            // last seg: 15 exact right odd-ext y (continue chain), zero-padded
            float xl = (float)tailB[7];
            float q[8];
            #pragma unroll
            for (int j = 0; j < 8; ++j) {
                float xe = fmaf(2.f, xl, -(float)(j < 7 ? tailB[6 - j] : tailA[14 - j]));
                STEPF(xe); q[j] = y;
            }
            int4 w0 = { PK(q[0], q[1]), PK(q[2], q[3]), PK(q[4], q[5]), PK(q[6], q[7]) };
            *(int4*)(Lb + 4160) = w0;
            float r[7];
            #pragma unroll
            for (int j = 8; j < 15; ++j) {
                float xe = fmaf(2.f, xl, -(float)tailA[14 - j]);
                STEPF(xe); r[j - 8] = y;
            }
            int4 w1 = { PK(r[0], r[1]), PK(r[2], r[3]), PK(r[4], r[5]), PK(r[6], 0.f) };
            *(int4*)(Lb + 4176) = w1;
            int4 zz = {0, 0, 0, 0};
            *(int4*)(Lb + 4192) = zz;
            *(int4*)(Lb + 4208) = zz;
        }
    }
    asm volatile("" ::: "memory");

    // ========= phase 3: bwd warm-up (28, neighbor Y / post W, descending) ==
    z1 = z2 = z3 = z4 = 0.f;
    {
        const int bb = (l + 2) * 64;
        const int xb = ((bb >> 7) & 7) << 4;
        h8 w3v = *(const h8*)(Lb + ((bb + 48) ^ xb));
        h8 w2v = *(const h8*)(Lb + ((bb + 32) ^ xb));
        h8 w1v = *(const h8*)(Lb + ((bb + 16) ^ xb));
        h8 w0v = *(const h8*)(Lb + ((bb +  0) ^ xb));
        STEPF((float)w3v[3]); STEPF((float)w3v[2]);
        STEPF((float)w3v[1]); STEPF((float)w3v[0]);
        #pragma unroll
        for (int e = 7; e >= 0; --e) STEPF((float)w2v[e]);
        #pragma unroll
        for (int e = 7; e >= 0; --e) STEPF((float)w1v[e]);
        #pragma unroll
        for (int e = 7; e >= 0; --e) STEPF((float)w0v[e]);
    }

    // ========= phase 4: bwd main (32, descending), out over Y in place =====
    {
        const int mb = (l + 1) * 64;
        const int xm = ((mb >> 7) & 7) << 4;
        #pragma unroll
        for (int j = 3; j >= 0; --j) {
            char* p = Lb + ((mb + 16 * j) ^ xm);
            h8 v = *(const h8*)p;
            float q[8];
            #pragma unroll
            for (int e = 7; e >= 0; --e) { STEPF((float)v[e]); q[e] = y; }
            int4 wi = { PK(q[0], q[1]), PK(q[2], q[3]), PK(q[4], q[5]), PK(q[6], q[7]) };
            *(int4*)p = wi;
        }
    }
    asm volatile("" ::: "memory");

    // ================= phase 5: coalesced fp16 LDS -> fp32 global ==========
    float4* op = (float4*)outr;
    #pragma unroll
    for (int i = 0; i < 8; ++i) {
        int lo = swz(64 + i * 512 + 8 * l);
        h4 hv = *(const h4*)(Lb + lo);
        float4 o = { (float)hv[0], (float)hv[1], (float)hv[2], (float)hv[3] };
        op[i * 64 + l] = o;
    }
}

extern "C" void kernel_launch(void* const* d_in, const int* in_sizes, int n_in,
                              void* d_out, int out_size, void* d_ws, size_t ws_size,
                              hipStream_t stream) {
    const float* x = (const float*)d_in[0];
    float* outp    = (float*)d_out;
    const int rows   = in_sizes[0] / kT;                  // 512
    const int blocks = rows * kNSeg * 64 / kTPB;          // 2048
    filtfilt_kernel<<<blocks, kTPB, 0, stream>>>(x, outp);
}